// Round 11
// baseline (294.991 us; speedup 1.0000x reference)
//
#include <hip/hip_runtime.h>

#define F_IN 512
#define HDIM 64
#define RSHIFT 7
#define RWIDTH 128
#define MAXNB 1024
#define CHUNK 4096

typedef _Float16 f16;
typedef _Float16 f16x2 __attribute__((ext_vector_type(2)));
typedef _Float16 f16x8 __attribute__((ext_vector_type(8)));
typedef float f32x4 __attribute__((ext_vector_type(4)));

// wsum[k] = sum_j linW[j][k]; wsum[64] = sum_j linB[j]
__global__ void prep_kernel(const float* __restrict__ linW,
                            const float* __restrict__ linB,
                            float* __restrict__ wsum) {
    int k = threadIdx.x;
    float s = 0.f;
    for (int j = 0; j < HDIM; ++j) s += linW[j * HDIM + k];
    wsum[k] = s;
    if (k == 0) {
        float b = 0.f;
        for (int j = 0; j < HDIM; ++j) b += linB[j];
        wsum[HDIM] = b;
    }
}

// fc_weight as f16 in B-fragment order:
// wf[((s*4 + c)*64 + lane)*8 + j] = W[c*16 + (lane&15)][s*32 + (lane>>4)*8 + j]
__global__ __launch_bounds__(256) void prep_w16_kernel(const float* __restrict__ W,
                                                       f16* __restrict__ wf) {
    int t = blockIdx.x * 256 + threadIdx.x;   // 0..4095
    int s = t >> 8;
    int c = (t >> 6) & 3;
    int l = t & 63;
    int row = c * 16 + (l & 15);
    int kb = s * 32 + ((l >> 4) << 3);
#pragma unroll
    for (int j = 0; j < 8; ++j)
        wf[(size_t)t * 8 + j] = (f16)W[row * F_IN + kb + j];
}

__global__ void zero_int_kernel(int* __restrict__ p, int n) {
    int i = blockIdx.x * blockDim.x + threadIdx.x;
    if (i < n) p[i] = 0;
}

// bucket histogram, LDS-pre-aggregated
__global__ __launch_bounds__(256) void bhist_kernel(const int* __restrict__ row,
                                                    int* __restrict__ bh,
                                                    int n_edges, int NB) {
    __shared__ int lh[MAXNB];
    for (int i = threadIdx.x; i < NB; i += 256) lh[i] = 0;
    __syncthreads();
    for (int e = blockIdx.x * 256 + threadIdx.x; e < n_edges; e += gridDim.x * 256)
        atomicAdd(&lh[row[e] >> RSHIFT], 1);
    __syncthreads();
    for (int i = threadIdx.x; i < NB; i += 256)
        if (lh[i]) atomicAdd(&bh[i], lh[i]);
}

// one block: exclusive scan of bh -> boff; init gcur; ptr[n_nodes] = n_edges
__global__ __launch_bounds__(1024) void bscan_kernel(const int* __restrict__ bh,
                                                     int* __restrict__ boff,
                                                     int* __restrict__ gcur,
                                                     int* __restrict__ ptr,
                                                     int NB, int n_nodes, int n_edges) {
    __shared__ int s[1024];
    const int t = threadIdx.x;
    int v = (t < NB) ? bh[t] : 0;
    s[t] = v;
    __syncthreads();
#pragma unroll
    for (int off = 1; off < 1024; off <<= 1) {
        int x = (t >= off) ? s[t - off] : 0;
        __syncthreads();
        s[t] += x;
        __syncthreads();
    }
    if (t < NB) {
        int o = s[t] - v;
        boff[t] = o;
        gcur[t] = o;
    }
    if (t == NB) boff[NB] = n_edges;
    if (t == 0) ptr[n_nodes] = n_edges;
}

// partition: per-block counting sort by bucket in LDS, append runs to global regions.
// record: (w_bits, col<<7 | row&127)
__global__ __launch_bounds__(256) void part_kernel(const int* __restrict__ row,
                                                   const int* __restrict__ col,
                                                   const float* __restrict__ w,
                                                   int* __restrict__ gcur,
                                                   int2* __restrict__ etmp,
                                                   int n_edges, int NB) {
    __shared__ int2 stg[CHUNK];             // 32 KB
    __shared__ unsigned short sbin[CHUNK];  // 8 KB
    __shared__ int lh[MAXNB];
    __shared__ int lofs[MAXNB];
    __shared__ int psum[256];
    const int t = threadIdx.x;
    const int base = blockIdx.x * CHUNK;
    const int cnt = min(CHUNK, n_edges - base);

    for (int i = t; i < NB; i += 256) lh[i] = 0;
    __syncthreads();
    for (int i = t; i < cnt; i += 256)
        atomicAdd(&lh[row[base + i] >> RSHIFT], 1);
    __syncthreads();
    int loc[4];
    int s0 = 0;
#pragma unroll
    for (int j = 0; j < 4; ++j) {
        int b = t * 4 + j;
        int c = (b < NB) ? lh[b] : 0;
        loc[j] = s0;
        s0 += c;
    }
    psum[t] = s0;
    __syncthreads();
#pragma unroll
    for (int off = 1; off < 256; off <<= 1) {
        int x = (t >= off) ? psum[t - off] : 0;
        __syncthreads();
        psum[t] += x;
        __syncthreads();
    }
    int pbase = psum[t] - s0;
#pragma unroll
    for (int j = 0; j < 4; ++j) {
        int b = t * 4 + j;
        if (b < NB) lofs[b] = pbase + loc[j];
    }
    __syncthreads();
    for (int i = t; i < cnt; i += 256) {
        int r = row[base + i];
        int b = r >> RSHIFT;
        int p = atomicAdd(&lofs[b], 1);
        stg[p] = make_int2(__float_as_int(w[base + i]),
                           (col[base + i] << RSHIFT) | (r & (RWIDTH - 1)));
        sbin[p] = (unsigned short)b;
    }
    __syncthreads();
    for (int b = t; b < NB; b += 256) {
        int c = lh[b];
        if (c) {
            int lstart = lofs[b] - c;
            int gb = atomicAdd(&gcur[b], c);
            lh[b] = gb - lstart;
        }
    }
    __syncthreads();
    for (int p = t; p < cnt; p += 256) {
        int b = sbin[p];
        etmp[lh[b] + p] = stg[p];
    }
}

// per-bucket counting sort -> full CSR order; write ptr. record out: (w_bits, col)
__global__ __launch_bounds__(256) void bsort_kernel(const int* __restrict__ boff,
                                                    const int2* __restrict__ etmp,
                                                    int2* __restrict__ ebin,
                                                    int* __restrict__ ptr,
                                                    int n_nodes) {
    __shared__ int nh[RWIDTH], lo[RWIDTH], lc[RWIDTH];
    const int b = blockIdx.x;
    const int t = threadIdx.x;
    const int e0 = boff[b], e1 = boff[b + 1];
    const int cnt = e1 - e0;
    if (t < RWIDTH) nh[t] = 0;
    __syncthreads();
    for (int i = t; i < cnt; i += 256)
        atomicAdd(&nh[etmp[e0 + i].y & (RWIDTH - 1)], 1);
    __syncthreads();
    if (t < RWIDTH) lo[t] = nh[t];
    __syncthreads();
    for (int off = 1; off < RWIDTH; off <<= 1) {
        int x = 0;
        if (t < RWIDTH && t >= off) x = lo[t - off];
        __syncthreads();
        if (t < RWIDTH) lo[t] += x;
        __syncthreads();
    }
    if (t < RWIDTH) {
        int ex = lo[t] - nh[t];               // exclusive
        lc[t] = ex;
        int node = b * RWIDTH + t;
        if (node < n_nodes) ptr[node] = e0 + ex;
    }
    __syncthreads();
    for (int i = t; i < cnt; i += 256) {
        int2 r = etmp[e0 + i];
        int p = atomicAdd(&lc[r.y & (RWIDTH - 1)], 1);
        ebin[e0 + p] = make_int2(r.x, r.y >> RSHIFT);
    }
}

// Both GCN fc passes per block over 64 rows, passes SEQUENTIAL (acc = 16 VGPR).
// Forced software pipeline: depth-2 A(X) prefetch + depth-1 B(wf) prefetch,
// pinned with sched_barrier(0) so the scheduler cannot sink the loads.
// Epilogue: LDS f16 tile [64][128] -> coalesced 64B/thread stores.
__global__ __launch_bounds__(256, 5) void gemm_both_kernel(const float* __restrict__ X1,
                                                           const float* __restrict__ X2,
                                                           const f16* __restrict__ wf,
                                                           f16* __restrict__ H,
                                                           int n_nodes) {
    __shared__ float4 tile_v[1024];   // 16 KB (epilogue tile)
    f16* tile = (f16*)tile_v;
    const int t = threadIdx.x;
    const int l = t & 63;
    const int w = t >> 6;
    const int m0 = blockIdx.x * 64;
    int arow = m0 + w * 16 + (l & 15);
    if (arow >= n_nodes) arow = n_nodes - 1;   // clamp loads; stores guarded
    const int g = l >> 4;
    const f16x8* wfv = reinterpret_cast<const f16x8*>(wf) + l;
    const int colj = l & 15;
    const int rbase = w * 16 + g * 4;

#pragma unroll
    for (int pass = 0; pass < 2; ++pass) {
        const float* xp = (pass ? X2 : X1) + (size_t)arow * F_IN + (g << 3);
        f32x4 ac0 = {}, ac1 = {}, ac2 = {}, ac3 = {};
        float4 Xa[3], Xb[3];
        f16x8 Bb[2][4];

        // prologue: A(0), A(1), B(0)
        Xa[0] = *reinterpret_cast<const float4*>(xp);
        Xb[0] = *reinterpret_cast<const float4*>(xp + 4);
        Xa[1] = *reinterpret_cast<const float4*>(xp + 32);
        Xb[1] = *reinterpret_cast<const float4*>(xp + 36);
        {
            const f16x8* bp = wfv;
            Bb[0][0] = bp[0]; Bb[0][1] = bp[64]; Bb[0][2] = bp[128]; Bb[0][3] = bp[192];
        }
#pragma unroll
        for (int c = 0; c < 16; ++c) {
            if (c + 2 < 16) {
                Xa[(c + 2) % 3] = *reinterpret_cast<const float4*>(xp + (c + 2) * 32);
                Xb[(c + 2) % 3] = *reinterpret_cast<const float4*>(xp + (c + 2) * 32 + 4);
            }
            if (c + 1 < 16) {
                const f16x8* bp = wfv + (size_t)(c + 1) * 256;
                Bb[(c + 1) & 1][0] = bp[0];
                Bb[(c + 1) & 1][1] = bp[64];
                Bb[(c + 1) & 1][2] = bp[128];
                Bb[(c + 1) & 1][3] = bp[192];
            }
            __builtin_amdgcn_sched_barrier(0);   // pin: prefetches stay above MFMAs
            float4 xa = Xa[c % 3], xb = Xb[c % 3];
            f16x8 a;
            a[0] = (f16)xa.x; a[1] = (f16)xa.y; a[2] = (f16)xa.z; a[3] = (f16)xa.w;
            a[4] = (f16)xb.x; a[5] = (f16)xb.y; a[6] = (f16)xb.z; a[7] = (f16)xb.w;
            ac0 = __builtin_amdgcn_mfma_f32_16x16x32_f16(a, Bb[c & 1][0], ac0, 0, 0, 0);
            ac1 = __builtin_amdgcn_mfma_f32_16x16x32_f16(a, Bb[c & 1][1], ac1, 0, 0, 0);
            ac2 = __builtin_amdgcn_mfma_f32_16x16x32_f16(a, Bb[c & 1][2], ac2, 0, 0, 0);
            ac3 = __builtin_amdgcn_mfma_f32_16x16x32_f16(a, Bb[c & 1][3], ac3, 0, 0, 0);
            __builtin_amdgcn_sched_barrier(0);
        }

        // dump this pass into the interleaved tile ([row][j*2+pass])
#pragma unroll
        for (int j = 0; j < 4; ++j) {
            f16* tp = tile + (rbase + j) * 128 + colj * 2 + pass;
            tp[0]  = (f16)ac0[j];
            tp[32] = (f16)ac1[j];
            tp[64] = (f16)ac2[j];
            tp[96] = (f16)ac3[j];
        }
    }

    __syncthreads();
    // coalesced store: 4 threads per 256B row, 64B each
    const int row = t >> 2;
    const int gm = m0 + row;
    if (gm < n_nodes) {
        const float4* sp = reinterpret_cast<const float4*>((char*)tile + row * 256 + (t & 3) * 64);
        float4* dp = reinterpret_cast<float4*>((char*)H + (size_t)gm * 256 + (t & 3) * 64);
#pragma unroll
        for (int q = 0; q < 4; ++q) dp[q] = sp[q];
    }
}

// per-node wave gather, BOTH passes at once; 4-deep load pipeline.
// h layout [node][j*2+pass]: lane loads f16x2 = both passes of feature `lane`.
__global__ __launch_bounds__(256) void agg_both_kernel(const int* __restrict__ ptr,
                                                       const int2* __restrict__ ebin,
                                                       const f16* __restrict__ h,
                                                       const float* __restrict__ gbias,
                                                       const float* __restrict__ wsum,
                                                       const float* __restrict__ prelu_a,
                                                       float* __restrict__ z,
                                                       int n_nodes) {
    const int lane = threadIdx.x & 63;
    const int wv = threadIdx.x >> 6;
    const int n = blockIdx.x * 4 + wv;
    if (n >= n_nodes) return;
    const f16x2* hv = reinterpret_cast<const f16x2*>(h) + lane;
    const int p0 = __builtin_amdgcn_readfirstlane(ptr[n]);
    const int p1 = __builtin_amdgcn_readfirstlane(ptr[n + 1]);
    float acc1 = 0.f, acc2 = 0.f;
    int i = p0;
    for (; i + 3 < p1; i += 4) {
        int2 e0 = ebin[i];
        int2 e1 = ebin[i + 1];
        int2 e2 = ebin[i + 2];
        int2 e3 = ebin[i + 3];
        f16x2 h0 = hv[(size_t)e0.y * HDIM];
        f16x2 h1 = hv[(size_t)e1.y * HDIM];
        f16x2 h2 = hv[(size_t)e2.y * HDIM];
        f16x2 h3 = hv[(size_t)e3.y * HDIM];
        float w0 = __int_as_float(e0.x), w1 = __int_as_float(e1.x);
        float w2 = __int_as_float(e2.x), w3 = __int_as_float(e3.x);
        acc1 = fmaf(w0, (float)h0[0], acc1);
        acc2 = fmaf(w0, (float)h0[1], acc2);
        acc1 = fmaf(w1, (float)h1[0], acc1);
        acc2 = fmaf(w1, (float)h1[1], acc2);
        acc1 = fmaf(w2, (float)h2[0], acc1);
        acc2 = fmaf(w2, (float)h2[1], acc2);
        acc1 = fmaf(w3, (float)h3[0], acc1);
        acc2 = fmaf(w3, (float)h3[1], acc2);
    }
    for (; i < p1; ++i) {
        int2 e0 = ebin[i];
        f16x2 h0 = hv[(size_t)e0.y * HDIM];
        float w0 = __int_as_float(e0.x);
        acc1 = fmaf(w0, (float)h0[0], acc1);
        acc2 = fmaf(w0, (float)h0[1], acc2);
    }
    const float a = prelu_a[0];
    const float gb = gbias[lane];
    const float wl = wsum[lane];
    float v1 = acc1 + gb;
    float v2 = acc2 + gb;
    v1 = (v1 >= 0.f) ? v1 : a * v1;
    v2 = (v2 >= 0.f) ? v2 : a * v2;
    float q1 = v1 * wl;
    float q2 = v2 * wl;
#pragma unroll
    for (int m = 32; m >= 1; m >>= 1) {
        q1 += __shfl_xor(q1, m, 64);
        q2 += __shfl_xor(q2, m, 64);
    }
    if (lane == 0) {
        z[n] = q1 + wsum[HDIM];
        z[n + n_nodes] = q2 + wsum[HDIM];
    }
}

// DIAGNOSTIC: pure streaming read of X1 -> measures achievable read BW in-context.
__global__ __launch_bounds__(256) void xread_bench_kernel(const float4* __restrict__ X,
                                                          float* __restrict__ sink,
                                                          long n4) {
    float acc = 0.f;
    for (long i = (long)blockIdx.x * 256 + threadIdx.x; i < n4; i += (long)gridDim.x * 256) {
        float4 v = X[i];
        acc += v.x + v.y + v.z + v.w;
    }
#pragma unroll
    for (int m = 32; m >= 1; m >>= 1) acc += __shfl_xor(acc, m, 64);
    if ((threadIdx.x & 63) == 0)
        sink[blockIdx.x * 4 + (threadIdx.x >> 6)] = acc;
}

extern "C" void kernel_launch(void* const* d_in, const int* in_sizes, int n_in,
                              void* d_out, int out_size, void* d_ws, size_t ws_size,
                              hipStream_t stream) {
    const float* x1    = (const float*)d_in[0];
    const float* x2    = (const float*)d_in[1];
    const int*   erow  = (const int*)d_in[2];
    const int*   ecol  = (const int*)d_in[3];
    const float* ew    = (const float*)d_in[4];
    const float* fcw   = (const float*)d_in[5];
    const float* gbias = (const float*)d_in[6];
    const float* pa    = (const float*)d_in[7];
    const float* linw  = (const float*)d_in[8];
    const float* linb  = (const float*)d_in[9];
    float* out = (float*)d_out;

    const int n_nodes = in_sizes[0] / F_IN;   // 100000
    const int n_edges = in_sizes[2];          // 1600000
    const int NB = (n_nodes + RWIDTH - 1) >> RSHIFT;   // 782

    // workspace layout
    f16*   h16  = (f16*)d_ws;                           // n_nodes*128 f16 (both passes)
    f16*   wf   = h16 + (size_t)n_nodes * 2 * HDIM;     // 64*512 f16
    int2*  etmp = (int2*)(wf + 64 * F_IN);              // n_edges int2
    int2*  ebin = etmp + n_edges;                       // n_edges int2
    int*   bh   = (int*)(ebin + n_edges);               // MAXNB
    int*   boff = bh + MAXNB;                           // MAXNB+1
    int*   gcur = boff + MAXNB + 1;                     // MAXNB
    int*   ptr  = gcur + MAXNB;                         // n_nodes+1
    float* wsum = (float*)(ptr + n_nodes + 1);          // 65 f32
    float* sink = wsum + 65;                            // 8192 f32 (diagnostic)

    prep_kernel<<<1, 64, 0, stream>>>(linw, linb, wsum);
    prep_w16_kernel<<<16, 256, 0, stream>>>(fcw, wf);

    zero_int_kernel<<<(NB + 255) / 256, 256, 0, stream>>>(bh, NB);
    bhist_kernel<<<256, 256, 0, stream>>>(erow, bh, n_edges, NB);
    bscan_kernel<<<1, 1024, 0, stream>>>(bh, boff, gcur, ptr, NB, n_nodes, n_edges);
    part_kernel<<<(n_edges + CHUNK - 1) / CHUNK, 256, 0, stream>>>(erow, ecol, ew, gcur,
                                                                   etmp, n_edges, NB);
    bsort_kernel<<<NB, 256, 0, stream>>>(boff, etmp, ebin, ptr, n_nodes);

    const int gemm_grid = (n_nodes + 63) / 64;
    const int fin_grid  = (n_nodes + 3) / 4;
    gemm_both_kernel<<<gemm_grid, 256, 0, stream>>>(x1, x2, wf, h16, n_nodes);
    agg_both_kernel<<<fin_grid, 256, 0, stream>>>(ptr, ebin, h16, gbias, wsum, pa,
                                                  out, n_nodes);

    // diagnostic last: streaming-read ceiling reference (writes only to scratch)
    xread_bench_kernel<<<2048, 256, 0, stream>>>((const float4*)x1, sink,
                                                 (long)n_nodes * F_IN / 4);
}

// Round 13
// 271.320 us; speedup vs baseline: 1.0872x; 1.0872x over previous
//
#include <hip/hip_runtime.h>

#define F_IN 512
#define HDIM 64
#define RSHIFT 7
#define RWIDTH 128
#define MAXNB 1024
#define CHUNK 4096

typedef _Float16 f16;
typedef _Float16 f16x2 __attribute__((ext_vector_type(2)));
typedef _Float16 f16x8 __attribute__((ext_vector_type(8)));
typedef float f32x4 __attribute__((ext_vector_type(4)));

#define GLOAD_LDS16(src, dst)                                                        \
    __builtin_amdgcn_global_load_lds((const __attribute__((address_space(1))) void*)(src), \
                                     (__attribute__((address_space(3))) void*)(dst), 16, 0, 0)

// wsum[k] = sum_j linW[j][k]; wsum[64] = sum_j linB[j]
__global__ void prep_kernel(const float* __restrict__ linW,
                            const float* __restrict__ linB,
                            float* __restrict__ wsum) {
    int k = threadIdx.x;
    float s = 0.f;
    for (int j = 0; j < HDIM; ++j) s += linW[j * HDIM + k];
    wsum[k] = s;
    if (k == 0) {
        float b = 0.f;
        for (int j = 0; j < HDIM; ++j) b += linB[j];
        wsum[HDIM] = b;
    }
}

// fc_weight as f16 in B-fragment order:
// wf[((s*4 + c)*64 + lane)*8 + j] = W[c*16 + (lane&15)][s*32 + (lane>>4)*8 + j]
__global__ __launch_bounds__(256) void prep_w16_kernel(const float* __restrict__ W,
                                                       f16* __restrict__ wf) {
    int t = blockIdx.x * 256 + threadIdx.x;   // 0..4095
    int s = t >> 8;
    int c = (t >> 6) & 3;
    int l = t & 63;
    int row = c * 16 + (l & 15);
    int kb = s * 32 + ((l >> 4) << 3);
#pragma unroll
    for (int j = 0; j < 8; ++j)
        wf[(size_t)t * 8 + j] = (f16)W[row * F_IN + kb + j];
}

__global__ void zero_int_kernel(int* __restrict__ p, int n) {
    int i = blockIdx.x * blockDim.x + threadIdx.x;
    if (i < n) p[i] = 0;
}

// bucket histogram, LDS-pre-aggregated
__global__ __launch_bounds__(256) void bhist_kernel(const int* __restrict__ row,
                                                    int* __restrict__ bh,
                                                    int n_edges, int NB) {
    __shared__ int lh[MAXNB];
    for (int i = threadIdx.x; i < NB; i += 256) lh[i] = 0;
    __syncthreads();
    for (int e = blockIdx.x * 256 + threadIdx.x; e < n_edges; e += gridDim.x * 256)
        atomicAdd(&lh[row[e] >> RSHIFT], 1);
    __syncthreads();
    for (int i = threadIdx.x; i < NB; i += 256)
        if (lh[i]) atomicAdd(&bh[i], lh[i]);
}

// one block: exclusive scan of bh -> boff; init gcur; ptr[n_nodes] = n_edges
__global__ __launch_bounds__(1024) void bscan_kernel(const int* __restrict__ bh,
                                                     int* __restrict__ boff,
                                                     int* __restrict__ gcur,
                                                     int* __restrict__ ptr,
                                                     int NB, int n_nodes, int n_edges) {
    __shared__ int s[1024];
    const int t = threadIdx.x;
    int v = (t < NB) ? bh[t] : 0;
    s[t] = v;
    __syncthreads();
#pragma unroll
    for (int off = 1; off < 1024; off <<= 1) {
        int x = (t >= off) ? s[t - off] : 0;
        __syncthreads();
        s[t] += x;
        __syncthreads();
    }
    if (t < NB) {
        int o = s[t] - v;
        boff[t] = o;
        gcur[t] = o;
    }
    if (t == NB) boff[NB] = n_edges;
    if (t == 0) ptr[n_nodes] = n_edges;
}

// partition: per-block counting sort by bucket in LDS, append runs to global regions.
// record: (w_bits, col<<7 | row&127)
__global__ __launch_bounds__(256) void part_kernel(const int* __restrict__ row,
                                                   const int* __restrict__ col,
                                                   const float* __restrict__ w,
                                                   int* __restrict__ gcur,
                                                   int2* __restrict__ etmp,
                                                   int n_edges, int NB) {
    __shared__ int2 stg[CHUNK];             // 32 KB
    __shared__ unsigned short sbin[CHUNK];  // 8 KB
    __shared__ int lh[MAXNB];
    __shared__ int lofs[MAXNB];
    __shared__ int psum[256];
    const int t = threadIdx.x;
    const int base = blockIdx.x * CHUNK;
    const int cnt = min(CHUNK, n_edges - base);

    for (int i = t; i < NB; i += 256) lh[i] = 0;
    __syncthreads();
    for (int i = t; i < cnt; i += 256)
        atomicAdd(&lh[row[base + i] >> RSHIFT], 1);
    __syncthreads();
    int loc[4];
    int s0 = 0;
#pragma unroll
    for (int j = 0; j < 4; ++j) {
        int b = t * 4 + j;
        int c = (b < NB) ? lh[b] : 0;
        loc[j] = s0;
        s0 += c;
    }
    psum[t] = s0;
    __syncthreads();
#pragma unroll
    for (int off = 1; off < 256; off <<= 1) {
        int x = (t >= off) ? psum[t - off] : 0;
        __syncthreads();
        psum[t] += x;
        __syncthreads();
    }
    int pbase = psum[t] - s0;
#pragma unroll
    for (int j = 0; j < 4; ++j) {
        int b = t * 4 + j;
        if (b < NB) lofs[b] = pbase + loc[j];
    }
    __syncthreads();
    for (int i = t; i < cnt; i += 256) {
        int r = row[base + i];
        int b = r >> RSHIFT;
        int p = atomicAdd(&lofs[b], 1);
        stg[p] = make_int2(__float_as_int(w[base + i]),
                           (col[base + i] << RSHIFT) | (r & (RWIDTH - 1)));
        sbin[p] = (unsigned short)b;
    }
    __syncthreads();
    for (int b = t; b < NB; b += 256) {
        int c = lh[b];
        if (c) {
            int lstart = lofs[b] - c;
            int gb = atomicAdd(&gcur[b], c);
            lh[b] = gb - lstart;
        }
    }
    __syncthreads();
    for (int p = t; p < cnt; p += 256) {
        int b = sbin[p];
        etmp[lh[b] + p] = stg[p];
    }
}

// per-bucket counting sort -> full CSR order; write ptr. record out: (w_bits, col)
__global__ __launch_bounds__(256) void bsort_kernel(const int* __restrict__ boff,
                                                    const int2* __restrict__ etmp,
                                                    int2* __restrict__ ebin,
                                                    int* __restrict__ ptr,
                                                    int n_nodes) {
    __shared__ int nh[RWIDTH], lo[RWIDTH], lc[RWIDTH];
    const int b = blockIdx.x;
    const int t = threadIdx.x;
    const int e0 = boff[b], e1 = boff[b + 1];
    const int cnt = e1 - e0;
    if (t < RWIDTH) nh[t] = 0;
    __syncthreads();
    for (int i = t; i < cnt; i += 256)
        atomicAdd(&nh[etmp[e0 + i].y & (RWIDTH - 1)], 1);
    __syncthreads();
    if (t < RWIDTH) lo[t] = nh[t];
    __syncthreads();
    for (int off = 1; off < RWIDTH; off <<= 1) {
        int x = 0;
        if (t < RWIDTH && t >= off) x = lo[t - off];
        __syncthreads();
        if (t < RWIDTH) lo[t] += x;
        __syncthreads();
    }
    if (t < RWIDTH) {
        int ex = lo[t] - nh[t];               // exclusive
        lc[t] = ex;
        int node = b * RWIDTH + t;
        if (node < n_nodes) ptr[node] = e0 + ex;
    }
    __syncthreads();
    for (int i = t; i < cnt; i += 256) {
        int2 r = etmp[e0 + i];
        int p = atomicAdd(&lc[r.y & (RWIDTH - 1)], 1);
        ebin[e0 + p] = make_int2(r.x, r.y >> RSHIFT);
    }
}

// Both GCN fc passes per block over 64 rows, passes SEQUENTIAL.
// High-occupancy async design: 16 KB LDS (2 x 8KB buffers, BK=32 f32),
// global_load_lds staging (zero staging VGPRs), row-minor LDS layout
// [kslice32B][q16B][row] -> linear DMA writes AND clean ds_reads, no swizzle.
// Per chunk: compute(c) -> issue STAGE(c+1)+B(c+1) -> barrier (drains both).
// Pass-0 result parked in 8 packed f16x2 regs. Epilogue tile reuses the 16 KB.
__global__ __launch_bounds__(256, 6) void gemm_both_kernel(const float* __restrict__ X1,
                                                           const float* __restrict__ X2,
                                                           const f16* __restrict__ wf,
                                                           f16* __restrict__ H,
                                                           int n_nodes) {
    __shared__ float4 lds4[1024];   // 16 KB
    char* xs = (char*)lds4;
    const int t = threadIdx.x;
    const int l = t & 63;
    const int w = t >> 6;
    const int m0 = blockIdx.x * 64;

    // staging: lane l stages ROW l; wave w covers chunk-bytes [w*32, w*32+32) (q=0,1)
    int srow = m0 + l;
    if (srow >= n_nodes) srow = n_nodes - 1;
    const char* sb1 = (const char*)(X1 + (size_t)srow * F_IN) + w * 32;
    const char* sb2 = (const char*)(X2 + (size_t)srow * F_IN) + w * 32;

    // compute: lane l of wave w -> row w*16+(l&15), k-group g = l>>4
    const int g = l >> 4;
    const int rl16 = (w * 16 + (l & 15)) * 16;
    const int a0 = g * 2048 + rl16;            // +buf*8192; +1024 for second 16B

    const f16x8* wfv = reinterpret_cast<const f16x8*>(wf) + l;
    const int colj = l & 15;
    const int rbase = w * 16 + g * 4;

    f32x4 ac0 = {}, ac1 = {}, ac2 = {}, ac3 = {};
    f16x8 B0, B1, B2, B3;
    f16x2 p0a, p0b, p1a, p1b, p2a, p2b, p3a, p3b;   // packed pass-0 result

#define STAGE(base, c, buf)                                                  \
    GLOAD_LDS16((base) + (c) * 128,      xs + (buf) * 8192 + w * 2048);      \
    GLOAD_LDS16((base) + (c) * 128 + 16, xs + (buf) * 8192 + w * 2048 + 1024);

#define LOADB(c)                                                             \
    { const f16x8* bp = wfv + (size_t)(c) * 256;                             \
      B0 = bp[0]; B1 = bp[64]; B2 = bp[128]; B3 = bp[192]; }

#define COMPUTE(buf)                                                              \
    {                                                                             \
        float4 xa = *reinterpret_cast<const float4*>(xs + (buf) * 8192 + a0);     \
        float4 xb = *reinterpret_cast<const float4*>(xs + (buf) * 8192 + a0 + 1024); \
        f16x8 a;                                                                  \
        a[0] = (f16)xa.x; a[1] = (f16)xa.y; a[2] = (f16)xa.z; a[3] = (f16)xa.w;   \
        a[4] = (f16)xb.x; a[5] = (f16)xb.y; a[6] = (f16)xb.z; a[7] = (f16)xb.w;   \
        ac0 = __builtin_amdgcn_mfma_f32_16x16x32_f16(a, B0, ac0, 0, 0, 0);        \
        ac1 = __builtin_amdgcn_mfma_f32_16x16x32_f16(a, B1, ac1, 0, 0, 0);        \
        ac2 = __builtin_amdgcn_mfma_f32_16x16x32_f16(a, B2, ac2, 0, 0, 0);        \
        ac3 = __builtin_amdgcn_mfma_f32_16x16x32_f16(a, B3, ac3, 0, 0, 0);        \
    }

    // ---------------- pass 0 (X1) ----------------
    STAGE(sb1, 0, 0)
    LOADB(0)
    __syncthreads();
#pragma unroll
    for (int c = 0; c < 16; ++c) {
        COMPUTE(c & 1)
        if (c < 15) {
            STAGE(sb1, c + 1, (c + 1) & 1)
            LOADB(c + 1)
        }
        __syncthreads();
    }
    p0a = f16x2{(f16)ac0[0], (f16)ac0[1]}; p0b = f16x2{(f16)ac0[2], (f16)ac0[3]};
    p1a = f16x2{(f16)ac1[0], (f16)ac1[1]}; p1b = f16x2{(f16)ac1[2], (f16)ac1[3]};
    p2a = f16x2{(f16)ac2[0], (f16)ac2[1]}; p2b = f16x2{(f16)ac2[2], (f16)ac2[3]};
    p3a = f16x2{(f16)ac3[0], (f16)ac3[1]}; p3b = f16x2{(f16)ac3[2], (f16)ac3[3]};
    ac0 = f32x4{}; ac1 = f32x4{}; ac2 = f32x4{}; ac3 = f32x4{};

    // ---------------- pass 1 (X2) ----------------
    STAGE(sb2, 0, 0)
    LOADB(0)
    __syncthreads();
#pragma unroll
    for (int c = 0; c < 16; ++c) {
        COMPUTE(c & 1)
        if (c < 15) {
            STAGE(sb2, c + 1, (c + 1) & 1)
            LOADB(c + 1)
        }
        __syncthreads();
    }
#undef STAGE
#undef LOADB
#undef COMPUTE

    // epilogue: tile [64 rows][128 f16] (j*2+pass interleave) -> coalesced stores
    {
        f16* tile = (f16*)xs;
        {
            f16* tp = tile + (rbase + 0) * 128 + colj * 2;
            tp[0] = p0a[0]; tp[32] = p1a[0]; tp[64] = p2a[0]; tp[96] = p3a[0];
            tp[1] = (f16)ac0[0]; tp[33] = (f16)ac1[0]; tp[65] = (f16)ac2[0]; tp[97] = (f16)ac3[0];
        }
        {
            f16* tp = tile + (rbase + 1) * 128 + colj * 2;
            tp[0] = p0a[1]; tp[32] = p1a[1]; tp[64] = p2a[1]; tp[96] = p3a[1];
            tp[1] = (f16)ac0[1]; tp[33] = (f16)ac1[1]; tp[65] = (f16)ac2[1]; tp[97] = (f16)ac3[1];
        }
        {
            f16* tp = tile + (rbase + 2) * 128 + colj * 2;
            tp[0] = p0b[0]; tp[32] = p1b[0]; tp[64] = p2b[0]; tp[96] = p3b[0];
            tp[1] = (f16)ac0[2]; tp[33] = (f16)ac1[2]; tp[65] = (f16)ac2[2]; tp[97] = (f16)ac3[2];
        }
        {
            f16* tp = tile + (rbase + 3) * 128 + colj * 2;
            tp[0] = p0b[1]; tp[32] = p1b[1]; tp[64] = p2b[1]; tp[96] = p3b[1];
            tp[1] = (f16)ac0[3]; tp[33] = (f16)ac1[3]; tp[65] = (f16)ac2[3]; tp[97] = (f16)ac3[3];
        }
        __syncthreads();
        const int row = t >> 2;            // 4 threads per 256B row
        const int gm = m0 + row;
        if (gm < n_nodes) {
            const float4* sp = reinterpret_cast<const float4*>(xs + row * 256 + (t & 3) * 64);
            float4* dp = reinterpret_cast<float4*>((char*)H + (size_t)gm * 256 + (t & 3) * 64);
#pragma unroll
            for (int q = 0; q < 4; ++q) dp[q] = sp[q];
        }
    }
}

// per-node wave gather, BOTH passes at once; 4-deep load pipeline.
// h layout [node][j*2+pass]: lane loads f16x2 = both passes of feature `lane`.
__global__ __launch_bounds__(256) void agg_both_kernel(const int* __restrict__ ptr,
                                                       const int2* __restrict__ ebin,
                                                       const f16* __restrict__ h,
                                                       const float* __restrict__ gbias,
                                                       const float* __restrict__ wsum,
                                                       const float* __restrict__ prelu_a,
                                                       float* __restrict__ z,
                                                       int n_nodes) {
    const int lane = threadIdx.x & 63;
    const int wv = threadIdx.x >> 6;
    const int n = blockIdx.x * 4 + wv;
    if (n >= n_nodes) return;
    const f16x2* hv = reinterpret_cast<const f16x2*>(h) + lane;
    const int p0 = __builtin_amdgcn_readfirstlane(ptr[n]);
    const int p1 = __builtin_amdgcn_readfirstlane(ptr[n + 1]);
    float acc1 = 0.f, acc2 = 0.f;
    int i = p0;
    for (; i + 3 < p1; i += 4) {
        int2 e0 = ebin[i];
        int2 e1 = ebin[i + 1];
        int2 e2 = ebin[i + 2];
        int2 e3 = ebin[i + 3];
        f16x2 h0 = hv[(size_t)e0.y * HDIM];
        f16x2 h1 = hv[(size_t)e1.y * HDIM];
        f16x2 h2 = hv[(size_t)e2.y * HDIM];
        f16x2 h3 = hv[(size_t)e3.y * HDIM];
        float w0 = __int_as_float(e0.x), w1 = __int_as_float(e1.x);
        float w2 = __int_as_float(e2.x), w3 = __int_as_float(e3.x);
        acc1 = fmaf(w0, (float)h0[0], acc1);
        acc2 = fmaf(w0, (float)h0[1], acc2);
        acc1 = fmaf(w1, (float)h1[0], acc1);
        acc2 = fmaf(w1, (float)h1[1], acc2);
        acc1 = fmaf(w2, (float)h2[0], acc1);
        acc2 = fmaf(w2, (float)h2[1], acc2);
        acc1 = fmaf(w3, (float)h3[0], acc1);
        acc2 = fmaf(w3, (float)h3[1], acc2);
    }
    for (; i < p1; ++i) {
        int2 e0 = ebin[i];
        f16x2 h0 = hv[(size_t)e0.y * HDIM];
        float w0 = __int_as_float(e0.x);
        acc1 = fmaf(w0, (float)h0[0], acc1);
        acc2 = fmaf(w0, (float)h0[1], acc2);
    }
    const float a = prelu_a[0];
    const float gb = gbias[lane];
    const float wl = wsum[lane];
    float v1 = acc1 + gb;
    float v2 = acc2 + gb;
    v1 = (v1 >= 0.f) ? v1 : a * v1;
    v2 = (v2 >= 0.f) ? v2 : a * v2;
    float q1 = v1 * wl;
    float q2 = v2 * wl;
#pragma unroll
    for (int m = 32; m >= 1; m >>= 1) {
        q1 += __shfl_xor(q1, m, 64);
        q2 += __shfl_xor(q2, m, 64);
    }
    if (lane == 0) {
        z[n] = q1 + wsum[HDIM];
        z[n + n_nodes] = q2 + wsum[HDIM];
    }
}

extern "C" void kernel_launch(void* const* d_in, const int* in_sizes, int n_in,
                              void* d_out, int out_size, void* d_ws, size_t ws_size,
                              hipStream_t stream) {
    const float* x1    = (const float*)d_in[0];
    const float* x2    = (const float*)d_in[1];
    const int*   erow  = (const int*)d_in[2];
    const int*   ecol  = (const int*)d_in[3];
    const float* ew    = (const float*)d_in[4];
    const float* fcw   = (const float*)d_in[5];
    const float* gbias = (const float*)d_in[6];
    const float* pa    = (const float*)d_in[7];
    const float* linw  = (const float*)d_in[8];
    const float* linb  = (const float*)d_in[9];
    float* out = (float*)d_out;

    const int n_nodes = in_sizes[0] / F_IN;   // 100000
    const int n_edges = in_sizes[2];          // 1600000
    const int NB = (n_nodes + RWIDTH - 1) >> RSHIFT;   // 782

    // workspace layout
    f16*   h16  = (f16*)d_ws;                           // n_nodes*128 f16 (both passes)
    f16*   wf   = h16 + (size_t)n_nodes * 2 * HDIM;     // 64*512 f16
    int2*  etmp = (int2*)(wf + 64 * F_IN);              // n_edges int2
    int2*  ebin = etmp + n_edges;                       // n_edges int2
    int*   bh   = (int*)(ebin + n_edges);               // MAXNB
    int*   boff = bh + MAXNB;                           // MAXNB+1
    int*   gcur = boff + MAXNB + 1;                     // MAXNB
    int*   ptr  = gcur + MAXNB;                         // n_nodes+1
    float* wsum = (float*)(ptr + n_nodes + 1);          // 65 f32

    prep_kernel<<<1, 64, 0, stream>>>(linw, linb, wsum);
    prep_w16_kernel<<<16, 256, 0, stream>>>(fcw, wf);

    zero_int_kernel<<<(NB + 255) / 256, 256, 0, stream>>>(bh, NB);
    bhist_kernel<<<256, 256, 0, stream>>>(erow, bh, n_edges, NB);
    bscan_kernel<<<1, 1024, 0, stream>>>(bh, boff, gcur, ptr, NB, n_nodes, n_edges);
    part_kernel<<<(n_edges + CHUNK - 1) / CHUNK, 256, 0, stream>>>(erow, ecol, ew, gcur,
                                                                   etmp, n_edges, NB);
    bsort_kernel<<<NB, 256, 0, stream>>>(boff, etmp, ebin, ptr, n_nodes);

    const int gemm_grid = (n_nodes + 63) / 64;
    const int fin_grid  = (n_nodes + 3) / 4;
    gemm_both_kernel<<<gemm_grid, 256, 0, stream>>>(x1, x2, wf, h16, n_nodes);
    agg_both_kernel<<<fin_grid, 256, 0, stream>>>(ptr, ebin, h16, gbias, wsum, pa,
                                                  out, n_nodes);
}